// Round 1
// baseline (229.452 us; speedup 1.0000x reference)
//
#include <hip/hip_runtime.h>

#define MASK_VALF 1000000000000.0f

typedef __attribute__((ext_vector_type(8))) short s16x8;   // 8 bf16 (4 VGPRs)
typedef __attribute__((ext_vector_type(4))) float f32x4;   // MFMA acc

__device__ __forceinline__ unsigned f2bf_u(float f) {
    union { float f; unsigned u; } v; v.f = f;
    return (v.u + 0x7FFFu + ((v.u >> 16) & 1u)) >> 16;  // RNE, low 16 bits valid
}
__device__ __forceinline__ short f2bf(float f) { return (short)(f2bf_u(f) & 0xFFFFu); }

// async global->LDS, 16B per lane; lds pointer must be wave-uniform base.
#define GLOAD16(gp, lp) __builtin_amdgcn_global_load_lds( \
    (const __attribute__((address_space(1))) void*)(gp),  \
    (__attribute__((address_space(3))) void*)(lp), 16, 0, 0)

// ---------------- fused prep: enc->bf16 | W transpose->bf16 | sincos table ----------------
__global__ __launch_bounds__(256) void prep_all(
    const float* __restrict__ enc, short* __restrict__ encb,
    const float* __restrict__ W, short* __restrict__ wtb,
    float* __restrict__ scf)
{
    const int blk = blockIdx.x;
    const int t = threadIdx.x;
    if (blk < 6144) {
        // enc f32 -> bf16, 4 elements/thread
        int i = blk * 256 + t;
        float4 v = ((const float4*)enc)[i];
        short4 o;
        o.x = f2bf(v.x); o.y = f2bf(v.y); o.z = f2bf(v.z); o.w = f2bf(v.w);
        ((short4*)encb)[i] = o;
    } else if (blk < 7008) {
        // W (768 x 1152) f32 -> Wt (1152 x 768) bf16, 32x32 tiles, 256 threads
        __shared__ float tile[32][33];
        int tb = blk - 6144;
        int tbx = tb % 36;       // n tile
        int tby = tb / 36;       // k tile
        int tx = t & 31, ty = t >> 5;
#pragma unroll
        for (int r = 0; r < 4; ++r) {
            int row = ty + r * 8;  // k within tile
            tile[row][tx] = W[(tby * 32 + row) * 1152 + tbx * 32 + tx];
        }
        __syncthreads();
#pragma unroll
        for (int r = 0; r < 4; ++r) {
            int row = ty + r * 8;  // n within tile
            wtb[(size_t)(tbx * 32 + row) * 768 + tby * 32 + tx] = f2bf(tile[tx][row]);
        }
    } else {
        // sincos table: [512 pos][32 j] of (cos, sin) pairs
        int id = (blk - 7008) * 256 + t;   // 0..16383
        int pos = id >> 5, j = id & 31;
        float inv = powf(10000.0f, -2.0f * (float)j / 64.0f);
        float ang = (float)pos * inv;
        float s, c;
        sincosf(ang, &s, &c);
        scf[id * 2]     = c;
        scf[id * 2 + 1] = s;
    }
}

// ---------------- GEMM1: Wt(1152x768) x enc(8192x768)^T + bias, RoPE -> qk bf16 ----------------
// Operands swapped (A=Wt, B=enc) so acc register index walks the OUTPUT COLUMN (dd):
// RoPE pairs live in adjacent registers -> no shfl; packed 8B stores.
// qk layout: [bh=144][qk=2][s=512][d=64]
__global__ __launch_bounds__(256) void gemm1_rope(
    const short* __restrict__ A,    // 8192x768 bf16 row-major (enc)
    const short* __restrict__ Bt,   // 1152x768 bf16 row-major (W^T)
    const float* __restrict__ bias, // 1152
    const float* __restrict__ scf,  // 512 x 64 floats (c,s interleaved)
    short* __restrict__ qk)
{
    __shared__ __align__(16) short As[128 * 32];
    __shared__ __align__(16) short Bs[128 * 32];
    const int t = threadIdx.x;
    const int w = t >> 6, lane = t & 63;
    const int lr = lane & 15, quad = lane >> 4;
    const int wm = w >> 1, wn = w & 1;   // wm: n-side 64-range, wn: m-side 64-range
    const int m0 = blockIdx.y * 128;     // rows of enc (pos dim)
    const int n0 = blockIdx.x * 128;     // cols (tag*128 + qk*64 + dd)

    f32x4 acc[4][4] = {};

    const short* gA = A  + (size_t)(m0 + (t >> 2)) * 768 + (t & 3) * 8;
    const short* gB = Bt + (size_t)(n0 + (t >> 2)) * 768 + (t & 3) * 8;
    short* lA0 = &As[w * 512];
    short* lA1 = &As[2048 + w * 512];
    short* lB0 = &Bs[w * 512];
    short* lB1 = &Bs[2048 + w * 512];

    for (int kt = 0; kt < 24; ++kt) {
        __syncthreads();
        GLOAD16(gA,            lA0);
        GLOAD16(gA + 64 * 768, lA1);
        GLOAD16(gB,            lB0);
        GLOAD16(gB + 64 * 768, lB1);
        gA += 32; gB += 32;
        __syncthreads();

        s16x8 af[4], bw[4];
#pragma unroll
        for (int i = 0; i < 4; ++i)   // A-operand = Wt rows (n dim)
            af[i] = *(const s16x8*)&Bs[(wm * 64 + i * 16 + lr) * 32 + quad * 8];
#pragma unroll
        for (int j = 0; j < 4; ++j)   // B-operand = enc rows (m dim)
            bw[j] = *(const s16x8*)&As[(wn * 64 + j * 16 + lr) * 32 + quad * 8];
#pragma unroll
        for (int i = 0; i < 4; ++i)
#pragma unroll
            for (int j = 0; j < 4; ++j)
                acc[i][j] = __builtin_amdgcn_mfma_f32_16x16x32_bf16(af[i], bw[j], acc[i][j], 0, 0, 0);
    }

    // epilogue: acc[i][j][r] = D[n = n0+wm*64+i*16+quad*4+r][m = m0+wn*64+j*16+lr]
#pragma unroll
    for (int i = 0; i < 4; ++i) {
        const int colg0 = n0 + wm * 64 + i * 16 + quad * 4;   // 4-aligned
        const float4 bv = *(const float4*)&bias[colg0];
        const int tag = colg0 >> 7;
        const int qkf = (colg0 >> 6) & 1;
        const int dd0 = colg0 & 63;
        const int jj0 = dd0 >> 1;                              // even
        short* qbase = qk + ((size_t)tag * 2 + qkf) * 512 * 64 + dd0;
#pragma unroll
        for (int j = 0; j < 4; ++j) {
            const int rowg = m0 + wn * 64 + j * 16 + lr;
            const int bidx = rowg >> 9;
            const int pos  = rowg & 511;
            const float4 cs = *(const float4*)&scf[pos * 64 + jj0 * 2]; // {c0,s0,c1,s1}
            float x0 = acc[i][j][0] + bv.x;
            float x1 = acc[i][j][1] + bv.y;
            float x2 = acc[i][j][2] + bv.z;
            float x3 = acc[i][j][3] + bv.w;
            float o0 = x0 * cs.x - x1 * cs.y;
            float o1 = x1 * cs.x + x0 * cs.y;
            float o2 = x2 * cs.z - x3 * cs.w;
            float o3 = x3 * cs.z + x2 * cs.w;
            int2 st;
            st.x = (int)(f2bf_u(o0) & 0xFFFFu) | (int)(f2bf_u(o1) << 16);
            st.y = (int)(f2bf_u(o2) & 0xFFFFu) | (int)(f2bf_u(o3) << 16);
            *(int2*)&qbase[((size_t)bidx * 9 * 2 * 512 + pos) * 64] = st;
        }
    }
}

// ---------------- GEMM2 v2: LDS-free. per (b,h): K(512x64) x Q(512x64)^T -> logits^T tile ----------------
// Previous version staged Q/K tiles in LDS with row stride 128B -> bank index
// (row*32 + quad*4)%32 is row-independent -> 16-way ds_read_b128 conflict (~5.7x).
// Each lane's MFMA fragment is a contiguous 16B slice of a qk row, so load it
// DIRECTLY from global (L2-resident, 128KB per bh slice): no LDS, no barriers,
// no conflicts. Output stream (147MB f32) is nontemporal so it doesn't evict qk.
__global__ __launch_bounds__(256) void gemm2_mask(
    const short* __restrict__ qk,
    const int* __restrict__ amask,   // (16,512) int32
    float* __restrict__ out)         // (16,9,512,512) f32
{
    const int t = threadIdx.x;
    const int w = t >> 6, lane = t & 63;
    const int lr = lane & 15, quad = lane >> 4;
    const int wm = w >> 1, wn = w & 1;   // wm: t-side, wn: s-side
    const int bh = blockIdx.z;
    const int bidx = bh / 9;
    const int s0 = blockIdx.y * 128;
    const int t0 = blockIdx.x * 128;

    const short* qbase = qk + (size_t)bh * 2 * 512 * 64;
    const short* kbase = qbase + 512 * 64;

    // per-lane fragment base pointers: row*64 shorts (128B) stride, quad*8 shorts (16B) column
    const short* kf = kbase + (size_t)(t0 + wm * 64 + lr) * 64 + quad * 8;
    const short* qf = qbase + (size_t)(s0 + wn * 64 + lr) * 64 + quad * 8;

    f32x4 acc[4][4] = {};
#pragma unroll
    for (int kk = 0; kk < 64; kk += 32) {
        s16x8 af[4], bw[4];
#pragma unroll
        for (int i = 0; i < 4; ++i)   // A-operand = K rows (t dim)
            af[i] = *(const s16x8*)&kf[i * 16 * 64 + kk];
#pragma unroll
        for (int j = 0; j < 4; ++j)   // B-operand = Q rows (s dim)
            bw[j] = *(const s16x8*)&qf[j * 16 * 64 + kk];
#pragma unroll
        for (int i = 0; i < 4; ++i)
#pragma unroll
            for (int j = 0; j < 4; ++j)
                acc[i][j] = __builtin_amdgcn_mfma_f32_16x16x32_bf16(af[i], bw[j], acc[i][j], 0, 0, 0);
    }

    // acc[i][j][r] = logits[s = s0+wn*64+j*16+lr][t = t0+wm*64+i*16+quad*4+r]
#pragma unroll
    for (int i = 0; i < 4; ++i) {
        const int tg0 = t0 + wm * 64 + i * 16 + quad * 4;   // 4-aligned
        const int4 am = *(const int4*)&amask[bidx * 512 + tg0];
        const float4 pad = make_float4((float)am.x, (float)am.y, (float)am.z, (float)am.w);
        const float4 mk = make_float4((1.0f - pad.x) * MASK_VALF, (1.0f - pad.y) * MASK_VALF,
                                      (1.0f - pad.z) * MASK_VALF, (1.0f - pad.w) * MASK_VALF);
#pragma unroll
        for (int j = 0; j < 4; ++j) {
            const int sg = s0 + wn * 64 + j * 16 + lr;
            f32x4 v;
            v[0] = (acc[i][j][0] * pad.x - mk.x - (sg > tg0     ? MASK_VALF : 0.0f)) * 0.125f;
            v[1] = (acc[i][j][1] * pad.y - mk.y - (sg > tg0 + 1 ? MASK_VALF : 0.0f)) * 0.125f;
            v[2] = (acc[i][j][2] * pad.z - mk.z - (sg > tg0 + 2 ? MASK_VALF : 0.0f)) * 0.125f;
            v[3] = (acc[i][j][3] * pad.w - mk.w - (sg > tg0 + 3 ? MASK_VALF : 0.0f)) * 0.125f;
            __builtin_nontemporal_store(v, (f32x4*)&out[((size_t)bh * 512 + sg) * 512 + tg0]);
        }
    }
}

extern "C" void kernel_launch(void* const* d_in, const int* in_sizes, int n_in,
                              void* d_out, int out_size, void* d_ws, size_t ws_size,
                              hipStream_t stream) {
    const float* enc   = (const float*)d_in[0];
    // d_in[1] = token_ids (unused by reference)
    const int*   amask = (const int*)d_in[2];
    const float* W     = (const float*)d_in[3];
    const float* bias  = (const float*)d_in[4];
    float* out = (float*)d_out;

    char* ws = (char*)d_ws;
    short* encb = (short*)(ws);                 // 8192*768*2   = 12,582,912 B
    short* wtb  = (short*)(ws + 12582912);      // 1152*768*2   =  1,769,472 B
    float* scf  = (float*)(ws + 14352384);      // 512*32*8     =    131,072 B
    short* qk   = (short*)(ws + 14483456);      // 144*2*512*64*2 = 18,874,368 B

    prep_all  <<<7072, 256, 0, stream>>>(enc, encb, W, wtb, scf);
    gemm1_rope<<<dim3(9, 64), 256, 0, stream>>>(encb, wtb, bias, scf, qk);
    gemm2_mask<<<dim3(4, 4, 144), 256, 0, stream>>>(qk, amask, out);
}